// Round 1
// 117.682 us; speedup vs baseline: 1.0099x; 1.0099x over previous
//
#include <hip/hip_runtime.h>

// ---------------- problem constants ----------------
#define T_LEN   1048576
#define NPAD    1049600            // T_LEN + 2*512 (bytes in i8 xpad, elems too)
#define NFRAMES 2049
#define BATCH   8
#define NJ      (BATCH * NFRAMES)  // 16392 total frames
#define NSEG    2050               // seg rows per batch
#define SMAX    (BATCH * NSEG - 1) // 16399
#define CUT     513
#define MROWS   1026
#define MPAD    1152               // 9 m-tiles of 128
#define OUT_BF  (CUT * NFRAMES)
#define NJT     129                // j-tiles of 128
#define PAD_BLOCKS (BATCH * (NPAD / 16) / 256)  // 2050
#define SB      28.222223f         // B scale = 127/4.5
#define INVS    (4.5f / 16129.f)   // 1/(127*SB)

typedef __attribute__((ext_vector_type(4))) int i32x4_t;

static __device__ __forceinline__ void gl_lds16(const char* g, char* s) {
    __builtin_amdgcn_global_load_lds(
        (__attribute__((address_space(1))) void*)g,
        (__attribute__((address_space(3))) void*)s,
        16, 0, 0);
}

static __device__ __forceinline__ char q127(float v, float scale) {
    return (char)(int)rintf(fminf(fmaxf(v * scale, -127.f), 127.f));
}

// ---------------- merged prep: reflect-pad + basis rearrange (both -> i8) ----------------
__global__ void prep_kernel(const float* __restrict__ in, const float* __restrict__ fb,
                            char* __restrict__ xpad, char* __restrict__ A2) {
    const int tid = threadIdx.x;
    if (blockIdx.x < PAD_BLOCKS) {
        int g  = blockIdx.x * 256 + tid;       // 16-elem chunk
        int b  = g / (NPAD / 16);
        int c  = g - b * (NPAD / 16);
        int i0 = c * 16;
        const float* inb = in + (size_t)b * T_LEN;
        union { char c[16]; ulonglong2 v; } u;
        if (i0 >= 512 && i0 + 15 < 512 + T_LEN) {
            #pragma unroll
            for (int t = 0; t < 16; t += 4) {
                const float4 v = *(const float4*)(inb + (i0 - 512) + t);
                u.c[t + 0] = q127(v.x, SB); u.c[t + 1] = q127(v.y, SB);
                u.c[t + 2] = q127(v.z, SB); u.c[t + 3] = q127(v.w, SB);
            }
        } else {
            for (int t = 0; t < 16; ++t) {
                int i = i0 + t;
                int src = (i < 512) ? (512 - i)
                        : (i < 512 + T_LEN) ? (i - 512)
                        : (2 * T_LEN + 510 - i);
                u.c[t] = q127(inb[src], SB);
            }
        }
        *(ulonglong2*)(xpad + (size_t)b * NPAD + i0) = u.v;
    } else {
        int g  = (blockIdx.x - PAD_BLOCKS) * 256 + tid;
        int r  = g >> 8;
        int cq = (g & 255) * 4;
        union { char c[4]; unsigned u; } o;
        if (r < MROWS) {
            int f = r >> 1, h = r & 1;
            const float4 v = *(const float4*)(fb + (size_t)(f + h * CUT) * 1024 + cq);
            o.c[0] = q127(v.x, 127.f); o.c[1] = q127(v.y, 127.f);
            o.c[2] = q127(v.z, 127.f); o.c[3] = q127(v.w, 127.f);
        } else {
            o.u = 0;
        }
        *(unsigned*)(A2 + (size_t)r * 1024 + cq) = o.u;
    }
}

// ---- GEMM i8, hop-split, BK=64, DOUBLE-BUFFERED LDS + prefetch (T3-minimal 2-phase) ----
// C[m][j] = sum_{k'<512} A0[m][k']*seg(Sj)[k'] + A1[m][k']*seg(Sj+1)[k']  (i32 exact)
// Per kt: STAGE(kt+1 -> buf^1) ; ds_read+MFMA on buf ; __syncthreads (drains the
// prefetch that flew under the MFMA phase). One barrier per kt, loads overlap compute.
// LDS per buffer: A0 [128][64] @0, A1 [128][64] @8192, B [144][64] @16384 (25600 B).
// 2 buffers = 50 KB -> 3 blocks/CU (same occupancy as before).
// Swizzle for 64-B rows: chunk ^= (row>>1)&3  (keeps <=2-way bank aliasing; the old
// (row&7) key would be 4-way here since a 64-B row spans only 16 banks).
__global__ __launch_bounds__(256) void gemm_kernel(
        const char* __restrict__ A2, const char* __restrict__ xpad,
        float* __restrict__ out, const float* __restrict__ epsp) {
    __shared__ __align__(16) char lds[2][25600];

    // XCD swizzle: all 9 m-blocks of one j-tile share bid%8 -> same XCD L2
    const int bid = blockIdx.x;
    const int jt  = (bid / 72) * 8 + (bid & 7);
    const int mt  = (bid >> 3) % 9;
    if (jt >= NJT) return;                 // uniform early-exit (before any barrier)

    const int tid  = threadIdx.x;
    const int wave = tid >> 6, lane = tid & 63;
    const int quad = lane >> 4, l15 = lane & 15;
    const int m0 = mt * 128;
    const int j0 = jt * 128;
    const int wm = (wave >> 1) * 64;
    const int wj = (wave & 1) * 64;

    const int b0 = j0 / NFRAMES;
    const int S0 = j0 + b0;                // global seg index of LDS B row 0

    // staging decomposition: one gl_lds16 call = 16 rows x 64 B
    const int lr = lane >> 2;                         // row within 16-row group
    const int sc = (((lane & 3) ^ ((lr >> 1) & 3)) * 16); // swizzled source chunk

    int aoff[2], boff[2], boffx = 0;
    for (int t = 0; t < 2; ++t) {
        const int ga = wave * 2 + t;       // group 0..7
        const int r  = ga * 16 + lr;       // LDS row 0..127
        aoff[t] = (m0 + r) * 1024 + sc;
        int S = S0 + r; if (S > SMAX) S = SMAX;
        int bb = S / NSEG, ss = S - bb * NSEG;
        boff[t] = bb * NPAD + ss * 512 + sc;
    }
    {   // extra B group 8: LDS rows 128..143 (only row <=129 is consumed)
        int S = S0 + 128 + lr; if (S > SMAX) S = SMAX;
        int bb = S / NSEG, ss = S - bb * NSEG;
        boffx = bb * NPAD + ss * 512 + sc;
    }

    // per-lane B fragment base rows (handles batch-boundary shift)
    int rowb[4];
    for (int jx = 0; jx < 4; ++jx) {
        const int j = j0 + wj + jx * 16 + l15;
        rowb[jx] = wj + jx * 16 + l15 + (j / NFRAMES - b0);
    }

    i32x4_t acc[4][4] = {};

#define STAGE(BUF, KB) do {                                                   \
        for (int t_ = 0; t_ < 2; ++t_) {                                      \
            const int ga_ = wave * 2 + t_;                                    \
            gl_lds16(A2 + aoff[t_] + (KB),        &lds[BUF][ga_ * 1024]);     \
            gl_lds16(A2 + aoff[t_] + 512 + (KB),  &lds[BUF][8192 + ga_ * 1024]); \
            gl_lds16(xpad + boff[t_] + (KB),      &lds[BUF][16384 + ga_ * 1024]); \
        }                                                                     \
        if (wave == 0) gl_lds16(xpad + boffx + (KB), &lds[BUF][16384 + 8192]); \
    } while (0)

    STAGE(0, 0);
    __syncthreads();                       // prologue drain (only unhidden load)

    #pragma unroll
    for (int kt = 0; kt < 8; ++kt) {
        const int buf = kt & 1;
        if (kt < 7) STAGE(buf ^ 1, (kt + 1) * 64);   // prefetch flies under MFMA

        const char* LA0 = &lds[buf][0];
        const char* LA1 = &lds[buf][8192];
        const char* LB  = &lds[buf][16384];

        i32x4_t a0[4], a1[4], bf0[4], bf1[4];
        const int asw = (quad ^ ((l15 >> 1) & 3)) * 16;
        for (int i = 0; i < 4; ++i) {
            const int ro = (wm + i * 16 + l15) * 64;
            a0[i] = *(const i32x4_t*)&LA0[ro + asw];
            a1[i] = *(const i32x4_t*)&LA1[ro + asw];
        }
        for (int jx = 0; jx < 4; ++jx) {
            const int r0 = rowb[jx];
            const int r1 = r0 + 1;
            bf0[jx] = *(const i32x4_t*)&LB[r0 * 64 + ((quad ^ ((r0 >> 1) & 3)) * 16)];
            bf1[jx] = *(const i32x4_t*)&LB[r1 * 64 + ((quad ^ ((r1 >> 1) & 3)) * 16)];
        }
        for (int i = 0; i < 4; ++i)
            for (int jx = 0; jx < 4; ++jx) {
                acc[i][jx] = __builtin_amdgcn_mfma_i32_16x16x64_i8(
                    a0[i], bf0[jx], acc[i][jx], 0, 0, 0);
                acc[i][jx] = __builtin_amdgcn_mfma_i32_16x16x64_i8(
                    a1[i], bf1[jx], acc[i][jx], 0, 0, 0);
            }

        if (kt < 7) __syncthreads();       // drains this iter's prefetch (vmcnt(0))
    }
#undef STAGE

    // epilogue: C/D layout col=lane&15 (-> j), row=quad*4+reg (-> M)
    const float eps = *epsp;
    for (int tj = 0; tj < 4; ++tj) {
        const int j = j0 + wj + tj * 16 + l15;
        if (j >= NJ) continue;
        const int b = j / NFRAMES;
        const int n = j - b * NFRAMES;
        float* ob = out + (size_t)b * OUT_BF + n;
        for (int ti = 0; ti < 4; ++ti) {
            const int M  = m0 + wm + ti * 16 + quad * 4;
            const int f0 = M >> 1;
            i32x4_t c = acc[ti][tj];
            float rx = c.x * INVS, ry = c.y * INVS;
            float rz = c.z * INVS, rw = c.w * INVS;
            if (f0 < CUT)
                ob[(size_t)f0 * NFRAMES] = sqrtf(rx * rx + ry * ry + eps);
            if (f0 + 1 < CUT)
                ob[(size_t)(f0 + 1) * NFRAMES] = sqrtf(rz * rz + rw * rw + eps);
        }
    }
}

extern "C" void kernel_launch(void* const* d_in, const int* in_sizes, int n_in,
                              void* d_out, int out_size, void* d_ws, size_t ws_size,
                              hipStream_t stream) {
    const float* in   = (const float*)d_in[0];
    const float* fb   = (const float*)d_in[1];
    const float* epsp = (const float*)d_in[2];
    float* out = (float*)d_out;

    char* A2   = (char*)d_ws;                               // MPAD*1024 B = 1.18 MB
    char* xpad = (char*)d_ws + (size_t)MPAD * 1024;         // 8*NPAD B = 8.4 MB

    prep_kernel<<<dim3(PAD_BLOCKS + MPAD), dim3(256), 0, stream>>>(in, fb, xpad, A2);
    // grid: 17 groups x (8 j-tiles x 9 m-tiles); blocks with jt>=129 early-exit
    gemm_kernel<<<dim3(17 * 72), dim3(256), 0, stream>>>(A2, xpad, out, epsp);
}

// Round 2
// 114.118 us; speedup vs baseline: 1.0415x; 1.0312x over previous
//
#include <hip/hip_runtime.h>

// ---------------- problem constants ----------------
#define T_LEN   1048576
#define NPAD    1049600            // T_LEN + 2*512 (bytes in i8 xpad, elems too)
#define NFRAMES 2049
#define BATCH   8
#define NJ      (BATCH * NFRAMES)  // 16392 total frames
#define NSEG    2050               // seg rows per batch
#define SMAX    (BATCH * NSEG - 1) // 16399
#define CUT     513
#define MROWS   1026
#define MPAD    1152               // 9 m-tiles of 128
#define OUT_BF  (CUT * NFRAMES)
#define NJT     129                // j-tiles of 128
#define PAD_BLOCKS (BATCH * (NPAD / 16) / 256)  // 2050
#define SB      28.222223f         // B scale = 127/4.5
#define INVS    (4.5f / 16129.f)   // 1/(127*SB)

typedef __attribute__((ext_vector_type(4))) int i32x4_t;

static __device__ __forceinline__ void gl_lds16(const char* g, char* s) {
    __builtin_amdgcn_global_load_lds(
        (__attribute__((address_space(1))) void*)g,
        (__attribute__((address_space(3))) void*)s,
        16, 0, 0);
}

static __device__ __forceinline__ char q127(float v, float scale) {
    return (char)(int)rintf(fminf(fmaxf(v * scale, -127.f), 127.f));
}

// ---------------- merged prep: reflect-pad + basis rearrange (both -> i8) ----------------
__global__ void prep_kernel(const float* __restrict__ in, const float* __restrict__ fb,
                            char* __restrict__ xpad, char* __restrict__ A2) {
    const int tid = threadIdx.x;
    if (blockIdx.x < PAD_BLOCKS) {
        int g  = blockIdx.x * 256 + tid;       // 16-elem chunk
        int b  = g / (NPAD / 16);
        int c  = g - b * (NPAD / 16);
        int i0 = c * 16;
        const float* inb = in + (size_t)b * T_LEN;
        union { char c[16]; ulonglong2 v; } u;
        if (i0 >= 512 && i0 + 15 < 512 + T_LEN) {
            #pragma unroll
            for (int t = 0; t < 16; t += 4) {
                const float4 v = *(const float4*)(inb + (i0 - 512) + t);
                u.c[t + 0] = q127(v.x, SB); u.c[t + 1] = q127(v.y, SB);
                u.c[t + 2] = q127(v.z, SB); u.c[t + 3] = q127(v.w, SB);
            }
        } else {
            for (int t = 0; t < 16; ++t) {
                int i = i0 + t;
                int src = (i < 512) ? (512 - i)
                        : (i < 512 + T_LEN) ? (i - 512)
                        : (2 * T_LEN + 510 - i);
                u.c[t] = q127(inb[src], SB);
            }
        }
        *(ulonglong2*)(xpad + (size_t)b * NPAD + i0) = u.v;
    } else {
        int g  = (blockIdx.x - PAD_BLOCKS) * 256 + tid;
        int r  = g >> 8;
        int cq = (g & 255) * 4;
        union { char c[4]; unsigned u; } o;
        if (r < MROWS) {
            int f = r >> 1, h = r & 1;
            const float4 v = *(const float4*)(fb + (size_t)(f + h * CUT) * 1024 + cq);
            o.c[0] = q127(v.x, 127.f); o.c[1] = q127(v.y, 127.f);
            o.c[2] = q127(v.z, 127.f); o.c[3] = q127(v.w, 127.f);
        } else {
            o.u = 0;
        }
        *(unsigned*)(A2 + (size_t)r * 1024 + cq) = o.u;
    }
}

// ---- GEMM i8, hop-split, BK=64, dbuf+prefetch, pinned 3 blocks/CU + setprio ----
// C[m][j] = sum_{k'<512} A0[m][k']*seg(Sj)[k'] + A1[m][k']*seg(Sj+1)[k']  (i32 exact)
// Per kt: STAGE(kt+1 -> buf^1) ; ds_read+MFMA on buf ; __syncthreads (drains the
// prefetch that flew under the MFMA phase). One barrier per kt.
// __launch_bounds__(256,3): pin 3 waves/SIMD = 3 blocks/CU (LDS 51.2KB*3=153.6<=160)
// so the register allocator cannot float VGPR past ~168 and silently drop occupancy.
// s_setprio(1) around the MFMA nest: with 3 independent blocks/CU at different
// phases, favors the compute wave over other blocks' staging waves (T5 condition).
__global__ __launch_bounds__(256, 3) void gemm_kernel(
        const char* __restrict__ A2, const char* __restrict__ xpad,
        float* __restrict__ out, const float* __restrict__ epsp) {
    __shared__ __align__(16) char lds[2][25600];

    // XCD swizzle: all 9 m-blocks of one j-tile share bid%8 -> same XCD L2
    const int bid = blockIdx.x;
    const int jt  = (bid / 72) * 8 + (bid & 7);
    const int mt  = (bid >> 3) % 9;
    if (jt >= NJT) return;                 // uniform early-exit (before any barrier)

    const int tid  = threadIdx.x;
    const int wave = tid >> 6, lane = tid & 63;
    const int quad = lane >> 4, l15 = lane & 15;
    const int m0 = mt * 128;
    const int j0 = jt * 128;
    const int wm = (wave >> 1) * 64;
    const int wj = (wave & 1) * 64;

    const int b0 = j0 / NFRAMES;
    const int S0 = j0 + b0;                // global seg index of LDS B row 0

    // staging decomposition: one gl_lds16 call = 16 rows x 64 B
    const int lr = lane >> 2;                         // row within 16-row group
    const int sc = (((lane & 3) ^ ((lr >> 1) & 3)) * 16); // swizzled source chunk

    int aoff[2], boff[2], boffx = 0;
    for (int t = 0; t < 2; ++t) {
        const int ga = wave * 2 + t;       // group 0..7
        const int r  = ga * 16 + lr;       // LDS row 0..127
        aoff[t] = (m0 + r) * 1024 + sc;
        int S = S0 + r; if (S > SMAX) S = SMAX;
        int bb = S / NSEG, ss = S - bb * NSEG;
        boff[t] = bb * NPAD + ss * 512 + sc;
    }
    {   // extra B group 8: LDS rows 128..143 (only row <=129 is consumed)
        int S = S0 + 128 + lr; if (S > SMAX) S = SMAX;
        int bb = S / NSEG, ss = S - bb * NSEG;
        boffx = bb * NPAD + ss * 512 + sc;
    }

    // per-lane B fragment base rows (handles batch-boundary shift)
    int rowb[4];
    for (int jx = 0; jx < 4; ++jx) {
        const int j = j0 + wj + jx * 16 + l15;
        rowb[jx] = wj + jx * 16 + l15 + (j / NFRAMES - b0);
    }

    i32x4_t acc[4][4] = {};

#define STAGE(BUF, KB) do {                                                   \
        for (int t_ = 0; t_ < 2; ++t_) {                                      \
            const int ga_ = wave * 2 + t_;                                    \
            gl_lds16(A2 + aoff[t_] + (KB),        &lds[BUF][ga_ * 1024]);     \
            gl_lds16(A2 + aoff[t_] + 512 + (KB),  &lds[BUF][8192 + ga_ * 1024]); \
            gl_lds16(xpad + boff[t_] + (KB),      &lds[BUF][16384 + ga_ * 1024]); \
        }                                                                     \
        if (wave == 0) gl_lds16(xpad + boffx + (KB), &lds[BUF][16384 + 8192]); \
    } while (0)

    STAGE(0, 0);
    __syncthreads();                       // prologue drain (only unhidden load)

    #pragma unroll
    for (int kt = 0; kt < 8; ++kt) {
        const int buf = kt & 1;
        if (kt < 7) STAGE(buf ^ 1, (kt + 1) * 64);   // prefetch flies under MFMA

        const char* LA0 = &lds[buf][0];
        const char* LA1 = &lds[buf][8192];
        const char* LB  = &lds[buf][16384];

        i32x4_t a0[4], a1[4], bf0[4], bf1[4];
        const int asw = (quad ^ ((l15 >> 1) & 3)) * 16;
        for (int i = 0; i < 4; ++i) {
            const int ro = (wm + i * 16 + l15) * 64;
            a0[i] = *(const i32x4_t*)&LA0[ro + asw];
            a1[i] = *(const i32x4_t*)&LA1[ro + asw];
        }
        for (int jx = 0; jx < 4; ++jx) {
            const int r0 = rowb[jx];
            const int r1 = r0 + 1;
            bf0[jx] = *(const i32x4_t*)&LB[r0 * 64 + ((quad ^ ((r0 >> 1) & 3)) * 16)];
            bf1[jx] = *(const i32x4_t*)&LB[r1 * 64 + ((quad ^ ((r1 >> 1) & 3)) * 16)];
        }
        __builtin_amdgcn_s_setprio(1);
        for (int i = 0; i < 4; ++i)
            for (int jx = 0; jx < 4; ++jx) {
                acc[i][jx] = __builtin_amdgcn_mfma_i32_16x16x64_i8(
                    a0[i], bf0[jx], acc[i][jx], 0, 0, 0);
                acc[i][jx] = __builtin_amdgcn_mfma_i32_16x16x64_i8(
                    a1[i], bf1[jx], acc[i][jx], 0, 0, 0);
            }
        __builtin_amdgcn_s_setprio(0);

        if (kt < 7) __syncthreads();       // drains this iter's prefetch (vmcnt(0))
    }
#undef STAGE

    // epilogue: C/D layout col=lane&15 (-> j), row=quad*4+reg (-> M)
    const float eps = *epsp;
    for (int tj = 0; tj < 4; ++tj) {
        const int j = j0 + wj + tj * 16 + l15;
        if (j >= NJ) continue;
        const int b = j / NFRAMES;
        const int n = j - b * NFRAMES;
        float* ob = out + (size_t)b * OUT_BF + n;
        for (int ti = 0; ti < 4; ++ti) {
            const int M  = m0 + wm + ti * 16 + quad * 4;
            const int f0 = M >> 1;
            i32x4_t c = acc[ti][tj];
            float rx = c.x * INVS, ry = c.y * INVS;
            float rz = c.z * INVS, rw = c.w * INVS;
            if (f0 < CUT)
                ob[(size_t)f0 * NFRAMES] = sqrtf(rx * rx + ry * ry + eps);
            if (f0 + 1 < CUT)
                ob[(size_t)(f0 + 1) * NFRAMES] = sqrtf(rz * rz + rw * rw + eps);
        }
    }
}

extern "C" void kernel_launch(void* const* d_in, const int* in_sizes, int n_in,
                              void* d_out, int out_size, void* d_ws, size_t ws_size,
                              hipStream_t stream) {
    const float* in   = (const float*)d_in[0];
    const float* fb   = (const float*)d_in[1];
    const float* epsp = (const float*)d_in[2];
    float* out = (float*)d_out;

    char* A2   = (char*)d_ws;                               // MPAD*1024 B = 1.18 MB
    char* xpad = (char*)d_ws + (size_t)MPAD * 1024;         // 8*NPAD B = 8.4 MB

    prep_kernel<<<dim3(PAD_BLOCKS + MPAD), dim3(256), 0, stream>>>(in, fb, xpad, A2);
    // grid: 17 groups x (8 j-tiles x 9 m-tiles); blocks with jt>=129 early-exit
    gemm_kernel<<<dim3(17 * 72), dim3(256), 0, stream>>>(A2, xpad, out, epsp);
}

// Round 3
// 113.035 us; speedup vs baseline: 1.0514x; 1.0096x over previous
//
#include <hip/hip_runtime.h>

// ---------------- problem constants ----------------
#define T_LEN   1048576
#define NPAD    1049600            // T_LEN + 2*512 (bytes in i8 xpad, elems too)
#define NFRAMES 2049
#define BATCH   8
#define NJ      (BATCH * NFRAMES)  // 16392 total frames
#define NSEG    2050               // seg rows per batch
#define SMAX    (BATCH * NSEG - 1) // 16399
#define CUT     513
#define MROWS   1026
#define MPAD    1152               // A2 rows allocated (light path uses row 1024)
#define OUT_BF  (CUT * NFRAMES)
#define NJT     129                // j-tiles of 128
#define PAD_BLOCKS (BATCH * (NPAD / 16) / 256)  // 2050
#define SB      28.222223f         // B scale = 127/4.5
#define INVS    (4.5f / 16129.f)   // 1/(127*SB)

typedef __attribute__((ext_vector_type(4))) int i32x4_t;

static __device__ __forceinline__ void gl_lds16(const char* g, char* s) {
    __builtin_amdgcn_global_load_lds(
        (__attribute__((address_space(1))) void*)g,
        (__attribute__((address_space(3))) void*)s,
        16, 0, 0);
}

static __device__ __forceinline__ char q127(float v, float scale) {
    return (char)(int)rintf(fminf(fmaxf(v * scale, -127.f), 127.f));
}

// ---------------- merged prep: reflect-pad + basis rearrange (both -> i8) ----------------
__global__ void prep_kernel(const float* __restrict__ in, const float* __restrict__ fb,
                            char* __restrict__ xpad, char* __restrict__ A2) {
    const int tid = threadIdx.x;
    if (blockIdx.x < PAD_BLOCKS) {
        int g  = blockIdx.x * 256 + tid;       // 16-elem chunk
        int b  = g / (NPAD / 16);
        int c  = g - b * (NPAD / 16);
        int i0 = c * 16;
        const float* inb = in + (size_t)b * T_LEN;
        union { char c[16]; ulonglong2 v; } u;
        if (i0 >= 512 && i0 + 15 < 512 + T_LEN) {
            #pragma unroll
            for (int t = 0; t < 16; t += 4) {
                const float4 v = *(const float4*)(inb + (i0 - 512) + t);
                u.c[t + 0] = q127(v.x, SB); u.c[t + 1] = q127(v.y, SB);
                u.c[t + 2] = q127(v.z, SB); u.c[t + 3] = q127(v.w, SB);
            }
        } else {
            for (int t = 0; t < 16; ++t) {
                int i = i0 + t;
                int src = (i < 512) ? (512 - i)
                        : (i < 512 + T_LEN) ? (i - 512)
                        : (2 * T_LEN + 510 - i);
                u.c[t] = q127(inb[src], SB);
            }
        }
        *(ulonglong2*)(xpad + (size_t)b * NPAD + i0) = u.v;
    } else {
        int g  = (blockIdx.x - PAD_BLOCKS) * 256 + tid;
        int r  = g >> 8;
        int cq = (g & 255) * 4;
        union { char c[4]; unsigned u; } o;
        if (r < MROWS) {
            int f = r >> 1, h = r & 1;
            const float4 v = *(const float4*)(fb + (size_t)(f + h * CUT) * 1024 + cq);
            o.c[0] = q127(v.x, 127.f); o.c[1] = q127(v.y, 127.f);
            o.c[2] = q127(v.z, 127.f); o.c[3] = q127(v.w, 127.f);
        } else {
            o.u = 0;
        }
        *(unsigned*)(A2 + (size_t)r * 1024 + cq) = o.u;
    }
}

// ---- GEMM i8, hop-split, BK=64, dbuf+prefetch, 3 blocks/CU pinned + setprio ----
// C[m][j] = sum_{k'<512} A0[m][k']*seg(Sj)[k'] + A1[m][k']*seg(Sj+1)[k']  (i32 exact)
// m-tiles 0..7 cover M rows 0..1023 (f=0..511) via MFMA. The former 9th m-tile was
// 98% zero-padding: f=512's imag basis row is -sin(pi*k)*win == 0 -> quantizes to
// exactly 0, so out[b][512][n] = sqrt((dot(A2row1024, frame)*INVS)^2 + eps) with
// BIT-IDENTICAL integer math to the MFMA result. mt==8 blocks now run that light
// dot-product path (2 threads/frame, sdot4), cutting heavy-block MFMA work by 11%.
__global__ __launch_bounds__(256, 3) void gemm_kernel(
        const char* __restrict__ A2, const char* __restrict__ xpad,
        float* __restrict__ out, const float* __restrict__ epsp) {
    __shared__ __align__(16) char lds[2][25600];

    // XCD swizzle: all 9 m-blocks of one j-tile share bid%8 -> same XCD L2
    const int bid = blockIdx.x;
    const int jt  = (bid / 72) * 8 + (bid & 7);
    const int mt  = (bid >> 3) % 9;
    if (jt >= NJT) return;                 // uniform early-exit (before any barrier)

    const int tid  = threadIdx.x;
    const int j0 = jt * 128;

    if (mt == 8) {
        // ---- Nyquist row f=512: one i8 dot per frame ----
        const int fi = tid >> 1, h = tid & 1;  // frame-in-tile, half (512 B each)
        const int j = j0 + fi;
        if (j < NJ) {
            const float eps = *epsp;
            const int b = j / NFRAMES;
            const int n = j - b * NFRAMES;
            // frame j = xpad[b][n*512 .. n*512+1024)
            const char* xp = xpad + (size_t)b * NPAD + (size_t)n * 512 + h * 512;
            const char* ap = A2 + (size_t)1024 * 1024 + h * 512;
            int s = 0;
            #pragma unroll
            for (int c = 0; c < 32; ++c) {
                const i32x4_t xa = *(const i32x4_t*)(ap + c * 16);
                const i32x4_t xb = *(const i32x4_t*)(xp + c * 16);
                #pragma unroll
                for (int q = 0; q < 4; ++q) {
#if __has_builtin(__builtin_amdgcn_sdot4)
                    s = __builtin_amdgcn_sdot4(xa[q], xb[q], s, false);
#else
                    const int av = xa[q], bv = xb[q];
                    #pragma unroll
                    for (int by = 0; by < 4; ++by)
                        s += (int)(char)(av >> (8 * by)) * (int)(char)(bv >> (8 * by));
#endif
                }
            }
            s += __shfl_xor(s, 1);
            if (h == 0) {
                const float r = s * INVS;
                out[(size_t)b * OUT_BF + (size_t)512 * NFRAMES + n] =
                    sqrtf(r * r + eps);
            }
        }
        return;
    }

    const int wave = tid >> 6, lane = tid & 63;
    const int quad = lane >> 4, l15 = lane & 15;
    const int m0 = mt * 128;
    const int wm = (wave >> 1) * 64;
    const int wj = (wave & 1) * 64;

    const int b0 = j0 / NFRAMES;
    const int S0 = j0 + b0;                // global seg index of LDS B row 0

    // staging decomposition: one gl_lds16 call = 16 rows x 64 B
    const int lr = lane >> 2;                         // row within 16-row group
    const int sc = (((lane & 3) ^ ((lr >> 1) & 3)) * 16); // swizzled source chunk

    int aoff[2], boff[2], boffx = 0;
    for (int t = 0; t < 2; ++t) {
        const int ga = wave * 2 + t;       // group 0..7
        const int r  = ga * 16 + lr;       // LDS row 0..127
        aoff[t] = (m0 + r) * 1024 + sc;
        int S = S0 + r; if (S > SMAX) S = SMAX;
        int bb = S / NSEG, ss = S - bb * NSEG;
        boff[t] = bb * NPAD + ss * 512 + sc;
    }
    {   // extra B group 8: LDS rows 128..143 (only row <=129 is consumed)
        int S = S0 + 128 + lr; if (S > SMAX) S = SMAX;
        int bb = S / NSEG, ss = S - bb * NSEG;
        boffx = bb * NPAD + ss * 512 + sc;
    }

    // per-lane B fragment base rows (handles batch-boundary shift)
    int rowb[4];
    for (int jx = 0; jx < 4; ++jx) {
        const int j = j0 + wj + jx * 16 + l15;
        rowb[jx] = wj + jx * 16 + l15 + (j / NFRAMES - b0);
    }

    i32x4_t acc[4][4] = {};

#define STAGE(BUF, KB) do {                                                   \
        for (int t_ = 0; t_ < 2; ++t_) {                                      \
            const int ga_ = wave * 2 + t_;                                    \
            gl_lds16(A2 + aoff[t_] + (KB),        &lds[BUF][ga_ * 1024]);     \
            gl_lds16(A2 + aoff[t_] + 512 + (KB),  &lds[BUF][8192 + ga_ * 1024]); \
            gl_lds16(xpad + boff[t_] + (KB),      &lds[BUF][16384 + ga_ * 1024]); \
        }                                                                     \
        if (wave == 0) gl_lds16(xpad + boffx + (KB), &lds[BUF][16384 + 8192]); \
    } while (0)

    STAGE(0, 0);
    __syncthreads();                       // prologue drain (only unhidden load)

    #pragma unroll
    for (int kt = 0; kt < 8; ++kt) {
        const int buf = kt & 1;
        if (kt < 7) STAGE(buf ^ 1, (kt + 1) * 64);   // prefetch flies under MFMA

        const char* LA0 = &lds[buf][0];
        const char* LA1 = &lds[buf][8192];
        const char* LB  = &lds[buf][16384];

        i32x4_t a0[4], a1[4], bf0[4], bf1[4];
        const int asw = (quad ^ ((l15 >> 1) & 3)) * 16;
        for (int i = 0; i < 4; ++i) {
            const int ro = (wm + i * 16 + l15) * 64;
            a0[i] = *(const i32x4_t*)&LA0[ro + asw];
            a1[i] = *(const i32x4_t*)&LA1[ro + asw];
        }
        for (int jx = 0; jx < 4; ++jx) {
            const int r0 = rowb[jx];
            const int r1 = r0 + 1;
            bf0[jx] = *(const i32x4_t*)&LB[r0 * 64 + ((quad ^ ((r0 >> 1) & 3)) * 16)];
            bf1[jx] = *(const i32x4_t*)&LB[r1 * 64 + ((quad ^ ((r1 >> 1) & 3)) * 16)];
        }
        __builtin_amdgcn_s_setprio(1);
        for (int i = 0; i < 4; ++i)
            for (int jx = 0; jx < 4; ++jx) {
                acc[i][jx] = __builtin_amdgcn_mfma_i32_16x16x64_i8(
                    a0[i], bf0[jx], acc[i][jx], 0, 0, 0);
                acc[i][jx] = __builtin_amdgcn_mfma_i32_16x16x64_i8(
                    a1[i], bf1[jx], acc[i][jx], 0, 0, 0);
            }
        __builtin_amdgcn_s_setprio(0);

        if (kt < 7) __syncthreads();       // drains this iter's prefetch (vmcnt(0))
    }
#undef STAGE

    // epilogue: C/D layout col=lane&15 (-> j), row=quad*4+reg (-> M)
    const float eps = *epsp;
    for (int tj = 0; tj < 4; ++tj) {
        const int j = j0 + wj + tj * 16 + l15;
        if (j >= NJ) continue;
        const int b = j / NFRAMES;
        const int n = j - b * NFRAMES;
        float* ob = out + (size_t)b * OUT_BF + n;
        for (int ti = 0; ti < 4; ++ti) {
            const int M  = m0 + wm + ti * 16 + quad * 4;
            const int f0 = M >> 1;
            i32x4_t c = acc[ti][tj];
            float rx = c.x * INVS, ry = c.y * INVS;
            float rz = c.z * INVS, rw = c.w * INVS;
            if (f0 < CUT)
                ob[(size_t)f0 * NFRAMES] = sqrtf(rx * rx + ry * ry + eps);
            if (f0 + 1 < CUT)
                ob[(size_t)(f0 + 1) * NFRAMES] = sqrtf(rz * rz + rw * rw + eps);
        }
    }
}

extern "C" void kernel_launch(void* const* d_in, const int* in_sizes, int n_in,
                              void* d_out, int out_size, void* d_ws, size_t ws_size,
                              hipStream_t stream) {
    const float* in   = (const float*)d_in[0];
    const float* fb   = (const float*)d_in[1];
    const float* epsp = (const float*)d_in[2];
    float* out = (float*)d_out;

    char* A2   = (char*)d_ws;                               // MPAD*1024 B = 1.18 MB
    char* xpad = (char*)d_ws + (size_t)MPAD * 1024;         // 8*NPAD B = 8.4 MB

    prep_kernel<<<dim3(PAD_BLOCKS + MPAD), dim3(256), 0, stream>>>(in, fb, xpad, A2);
    // grid: 17 groups x (8 j-tiles x 9 m-slots); mt==8 = Nyquist light path
    gemm_kernel<<<dim3(17 * 72), dim3(256), 0, stream>>>(A2, xpad, out, epsp);
}